// Round 8
// baseline (86789.453 us; speedup 1.0000x reference)
//
#include <hip/hip_runtime.h>
#include <math.h>

// ---------------------------------------------------------------------------
// FastFFTNet autoregressive sampler on MI355X — round 8: R7 tagged-payload
// pipeline with comms moved from relaxed store/load (write-through to HBM,
// polls = HBM fetches; R7 counters: 101 KB/step HBM reads + 90 KB/step HBM
// writes = the comm volume) to ATOMIC RMW pairs that execute at the
// memory-side LLC (coherent point): producer = u64 atomic_exchange,
// consumer = u64 CAS with impossible-expected (not foldable to a plain
// load, unlike idempotent fetch_add 0). Everything else byte-identical
// to R7 (passed, absmax 0).
//
// Roles (32 blocks x 512 thr): 0 sampler | 1 L0 | 2..11 A_j (j=role-1)
//   12..21 B_j (j=role-11) | 22..31 helper_j (j=role-21, past taps)
// ---------------------------------------------------------------------------

#define T_STEPS 2048
#define NROLE   32

typedef unsigned long long u64;
typedef float v64f __attribute__((ext_vector_type(64)));

// ws float offsets
#define OFF_EMBT   0           // tanh(emb_raw)           [256][256]
#define OFF_WPET   65536       // WV_present[0] @ emb^T   [class][256]
#define OFF_WVPET  131072      // WV_past[0]    @ emb^T   [class][256]
#define OFF_RINGS  196608      // ring_j (plain f32) at +512*((1<<j)-1), 512<<j floats
#define OFF_TAPQ   1244672     // pairs [10][32][256]
#define OFF_ZQ     1408512     // pairs [11][2][256] (j=1..10 used)
#define OFF_XQ     1419776     // pairs [11][256]    (x_j; j=1 from L0, j>=2 from A_j)
#define WS_FLOATS  1425408

#define FIDX     0             // int index into iflags
#define FBAR(r)  (32 + 32*(r)) // init barriers; poison-safe monotone

// impossible tag sentinels (real tags are 1..2049, FIDX values < 2051<<8)
#define QSENT1 0x7fffffff00000000ull
#define QSENT2 0x7ffffffe00000000ull
#define ISENT1 0x7fffffff
#define ISENT2 0x7ffffffe

// ---- agent-scope plain prims (init + helper ring path; proven) ------------
__device__ __forceinline__ float ldc(const float* p) {
  int v = __hip_atomic_load((const int*)p, __ATOMIC_RELAXED, __HIP_MEMORY_SCOPE_AGENT);
  return __int_as_float(v);
}
__device__ __forceinline__ void stc(float* p, float x) {
  __hip_atomic_store((int*)p, __float_as_int(x), __ATOMIC_RELAXED, __HIP_MEMORY_SCOPE_AGENT);
}

// ---- LLC-resident comm prims: atomic RMW pairs ----------------------------
__device__ __forceinline__ u64 ldq(u64* p) {
  u64 e = QSENT1;
  __hip_atomic_compare_exchange_strong(p, &e, QSENT2, __ATOMIC_RELAXED,
                                       __ATOMIC_RELAXED, __HIP_MEMORY_SCOPE_AGENT);
  return e;   // CAS always fails (tags never reach sentinel) -> returns current
}
__device__ __forceinline__ void stq(u64* p, float v, int tag) {
  u64 x = (u64)(unsigned)__float_as_int(v) | ((u64)(unsigned)tag << 32);
  (void)__hip_atomic_exchange(p, x, __ATOMIC_RELAXED, __HIP_MEMORY_SCOPE_AGENT);
}
__device__ __forceinline__ int ld_fidx(int* p) {
  int e = ISENT1;
  __hip_atomic_compare_exchange_strong(p, &e, ISENT2, __ATOMIC_RELAXED,
                                       __ATOMIC_RELAXED, __HIP_MEMORY_SCOPE_AGENT);
  return e;
}
__device__ __forceinline__ void st_fidx(int* p, int v) {
  (void)__hip_atomic_exchange(p, v, __ATOMIC_RELAXED, __HIP_MEMORY_SCOPE_AGENT);
}
__device__ __forceinline__ int ptag(u64 q) { return (int)(q >> 32); }
__device__ __forceinline__ float pval(u64 q) { return __int_as_float((int)(unsigned)q); }

__device__ __forceinline__ float spin_pair(u64* p, int want) {
  int bud = 1 << 20; u64 q;
  do { q = ldq(p); } while (ptag(q) < want && --bud > 0);
  return pval(q);
}
__device__ __forceinline__ void spin3(u64* p1, u64* p2, u64* p3,
                                      int want, float& v1, float& v2, float& v3) {
  int bud = 1 << 20; u64 q1, q2, q3; bool ok;
  do {
    q1 = ldq(p1); q2 = ldq(p2); q3 = ldq(p3);
    ok = (ptag(q1) >= want) & (ptag(q2) >= want) & (ptag(q3) >= want);
  } while (!ok && --bud > 0);
  v1 = pval(q1); v2 = pval(q2); v3 = pval(q3);
}
__device__ __forceinline__ void spin_tag2(u64* p1, u64* p2, int w1, int w2) {
  int bud = 1 << 20; u64 q1, q2; bool ok;
  do {
    q1 = ldq(p1); q2 = ldq(p2);
    ok = (ptag(q1) >= w1) & (ptag(q2) >= w2);
  } while (!ok && --bud > 0);
}
// init-phase flag prims (proven)
__device__ __forceinline__ void wait1(int* f, int want) {
  int it = 0;
  while (__hip_atomic_load(f, __ATOMIC_RELAXED, __HIP_MEMORY_SCOPE_AGENT) < want) {
    if (++it > (1 << 22)) break;
  }
  (void)__hip_atomic_load(f, __ATOMIC_ACQUIRE, __HIP_MEMORY_SCOPE_AGENT);
}
__device__ __forceinline__ void post(int* f, int v) {
  __hip_atomic_store(f, v, __ATOMIC_RELEASE, __HIP_MEMORY_SCOPE_AGENT);
}

__global__ __launch_bounds__(512, 1)
void fftnet_kernel(const float* __restrict__ y, const float* __restrict__ samples,
                   const float* __restrict__ emb_raw, const float* __restrict__ condW,
                   const float* __restrict__ WV_past, const float* __restrict__ WV_present,
                   const float* __restrict__ W_o_w, const float* __restrict__ W_o_b,
                   const float* __restrict__ end_w, const float* __restrict__ end_b,
                   int* __restrict__ out, float* __restrict__ ws)
{
  const int tid = threadIdx.x;
  const int role = blockIdx.x;
  int* iflags = (int*)(ws + WS_FLOATS);
  u64* zq  = (u64*)(ws + OFF_ZQ);
  u64* xq  = (u64*)(ws + OFF_XQ);
  u64* tq  = (u64*)(ws + OFF_TAPQ);

  __shared__ float s_x[256];
  __shared__ float s_h[256];
  __shared__ float s_p[1024];
  __shared__ float s_cond[16 * 256];
  __shared__ float s_tap[128];
  __shared__ float s_m[320];
  __shared__ unsigned long long s_mask[8];

  // ---- init B: embt = tanh(emb_raw) ---------------------------------------
  for (int i = role * 512 + tid; i < 65536; i += NROLE * 512)
    stc(ws + OFF_EMBT + i, tanhf(emb_raw[i]));
  __syncthreads();
  if (tid == 0) post(iflags + FBAR(role), 1);
  if (tid < NROLE) wait1(iflags + FBAR(tid), 1);
  __syncthreads();

  // ---- init C: WPEt / WVP0Et tables ---------------------------------------
  for (int n = role; n < 512; n += NROLE) {
    const float* wmat = (n < 256) ? WV_present : WV_past;  // layer-0 slice
    int cls = n & 255;
    int c = tid & 255, s2 = tid >> 8;
    float acc = 0.f;
    for (int k = 128 * s2; k < 128 * s2 + 128; ++k)
      acc += wmat[c * 256 + k] * ws[OFF_EMBT + cls * 256 + k];
    s_p[s2 * 256 + c] = acc;
    __syncthreads();
    if (tid < 256)
      stc(ws + ((n < 256) ? OFF_WPET : OFF_WVPET) + cls * 256 + tid, s_p[tid] + s_p[256 + tid]);
    __syncthreads();
  }
  __syncthreads();
  if (tid == 0) post(iflags + FBAR(role), 2);
  if (tid < NROLE) wait1(iflags + FBAR(tid), 2);
  __syncthreads();
  __builtin_amdgcn_fence(__ATOMIC_ACQUIRE, "agent");   // invalidate stale L1
  __syncthreads();

  // =========================================================================
  if (role == 0) {
    // ------------------------- sampler -------------------------------------
    const int c = tid & 255, s2 = tid >> 8;
    v64f we0, we1;
#pragma unroll
    for (int i = 0; i < 64; ++i) we0[i] = end_w[c * 256 + 128 * s2 + i];
#pragma unroll
    for (int i = 0; i < 64; ++i) we1[i] = end_w[c * 256 + 128 * s2 + 64 + i];
    const float eb = end_b[c];
    const float b10 = W_o_b[10 * 256 + c];
    u64* pza = zq + (10 * 2 + 0) * 256;
    u64* pzb = zq + (10 * 2 + 1) * 256;
    u64* pxq = xq + 10 * 256;
    const int lane = tid & 63, w = tid >> 6;
    if (tid == 0) st_fidx(iflags + FIDX, (1 << 8) | 127);

    for (int t = 0; t < T_STEPS; ++t) {
      float u = samples[t];
      if (tid < 256) {
        float a, b, r3;
        spin3(pza + tid, pzb + tid, pxq + tid, t + 1, a, b, r3);
        s_x[tid] = fmaxf(a + b + b10 + r3, 0.f);
      }
      __syncthreads();
      float acc = 0.f;
#pragma unroll
      for (int i = 0; i < 64; ++i) acc += we0[i] * s_x[128 * s2 + i];
#pragma unroll
      for (int i = 0; i < 64; ++i) acc += we1[i] * s_x[128 * s2 + 64 + i];
      s_p[s2 * 256 + c] = acc;
      __syncthreads();
      float logit = 0.f;
      if (tid < 256) logit = s_p[tid] + s_p[256 + tid] + eb;
      float vmax = (tid < 256) ? logit : -3.4e38f;
#pragma unroll
      for (int d = 32; d > 0; d >>= 1) vmax = fmaxf(vmax, __shfl_xor(vmax, d, 64));
      if (lane == 0) s_m[280 + w] = vmax;
      __syncthreads();
      float mx = fmaxf(fmaxf(s_m[280], s_m[281]), fmaxf(s_m[282], s_m[283]));
      float e = (tid < 256) ? expf(logit - mx) : 0.f;
      float vs = e;
#pragma unroll
      for (int d = 32; d > 0; d >>= 1) vs += __shfl_xor(vs, d, 64);
      if (lane == 0) s_m[288 + w] = vs;
      __syncthreads();
      float ssum = s_m[288] + s_m[289] + s_m[290] + s_m[291];
      float p = (tid < 256) ? (e / ssum) : 0.f;
      float v = p;
#pragma unroll
      for (int d = 1; d < 64; d <<= 1) {
        float o = __shfl_up(v, (unsigned)d, 64);
        if (lane >= d) v += o;
      }
      if (tid < 256 && lane == 63) s_m[256 + w] = v;
      __syncthreads();
      float offs = 0.f;
      if (tid < 256) for (int k = 0; k < w; ++k) offs += s_m[256 + k];
      float cum = v + offs;
      unsigned long long msk = __ballot(tid < 256 && (cum > u));
      if (lane == 0) s_mask[w] = msk;
      __syncthreads();
      if (tid == 0) {
        int idx = 0;
        for (int k = 0; k < 4; ++k) {
          unsigned long long m2 = s_mask[k];
          if (m2) { idx = k * 64 + (int)__builtin_ctzll(m2); break; }
        }
        st_fidx(iflags + FIDX, ((t + 2) << 8) | idx);
        out[t] = idx;
      }
      __syncthreads();
    }

  } else if (role == 1) {
    // ------------------------- L0: idx -> x1 (tagged) -----------------------
    v64f wo00, wo01;
    { int c = tid & 255, s2 = tid >> 8;
#pragma unroll
      for (int i = 0; i < 64; ++i) wo00[i] = W_o_w[c * 256 + 128 * s2 + i];
#pragma unroll
      for (int i = 0; i < 64; ++i) wo01[i] = W_o_w[c * 256 + 128 * s2 + 64 + i]; }
    const float b0 = W_o_b[tid & 255];
    for (int e = tid; e < 4096; e += 512) {
      int f = e >> 8, r = e & 255;
      float a = 0.f;
      for (int q = 0; q < 80; ++q) a += condW[r * 80 + q] * y[q * 16 + f];
      s_cond[f * 256 + r] = a;
    }
    __syncthreads();
    u64* px1 = xq + 1 * 256;
    int pidx = 127;

    for (int t = 0; t < T_STEPS; ++t) {
      float tapv = 0.f;
      if (tid < 256 && t > 0) tapv = ws[OFF_WVPET + pidx * 256 + tid];  // prefetch
      int v, bud = 1 << 20;
      do { v = ld_fidx(iflags + FIDX); } while (v < ((t + 1) << 8) && --bud > 0);
      const int idx = v & 255;
      if (tid < 256) {
        s_x[tid] = ws[OFF_EMBT + idx * 256 + tid];
        float hv = s_cond[(t >> 7) * 256 + tid] + ws[OFF_WPET + idx * 256 + tid] + tapv;
        s_h[tid] = fmaxf(hv, 0.f);
      }
      __syncthreads();
      { int c = tid & 255, s2 = tid >> 8;
        float a0 = 0.f, a1 = 0.f;
#pragma unroll
        for (int i = 0; i < 64; ++i) a0 += wo00[i] * s_h[128 * s2 + i];
#pragma unroll
        for (int i = 0; i < 64; ++i) a1 += wo01[i] * s_h[128 * s2 + 64 + i];
        s_p[s2 * 256 + c] = a0 + a1;
      }
      __syncthreads();
      if (tid < 256)
        stq(px1 + tid, fmaxf(s_p[tid] + s_p[256 + tid] + b0 + s_x[tid], 0.f), t + 1);
      pidx = idx;
    }

  } else if (role <= 21) {
    // ------------------------- layer stages A/B (j = 1..10) -----------------
    const int jj = (role <= 11) ? (role - 1) : (role - 11);
    const int side = (role <= 11) ? 0 : 1;
    const int base = side * 128;
    v64f wpv, wov;
    { const float* W = WV_present + jj * 65536;
      int r = tid & 127, s = tid >> 7;
#pragma unroll
      for (int i = 0; i < 64; ++i) wpv[i] = W[(base + r) * 256 + 64 * s + i]; }
    { const float* W = W_o_w + jj * 65536;
      int c = tid & 255, s2 = tid >> 8;
#pragma unroll
      for (int i = 0; i < 64; ++i) wov[i] = W[c * 256 + base + 64 * s2 + i]; }
    const float bprev = W_o_b[(jj - 1) * 256 + (tid & 255)];
    for (int e = tid; e < 2048; e += 512) {
      int f = e >> 7, rr = e & 127;
      float a = 0.f;
      for (int q = 0; q < 80; ++q) a += condW[(jj * 256 + base + rr) * 80 + q] * y[q * 16 + f];
      s_cond[f * 128 + rr] = a;
    }
    __syncthreads();
    const int dj = 1 << jj, maskj = 2 * dj - 1;
    float* ringj = ws + OFF_RINGS + 512 * (dj - 1);
    u64* pza = zq + ((jj - 1) * 2 + 0) * 256;
    u64* pzb = zq + ((jj - 1) * 2 + 1) * 256;
    u64* pxp = xq + (jj - 1) * 256;
    u64* zout = zq + (jj * 2 + side) * 256;
    u64* xout = xq + jj * 256;
    u64* ptap = tq + (jj - 1) * 32 * 256;

    for (int t = 0; t < T_STEPS; ++t) {
      const int want = t + 1;
      if (tid < 256) {
        float xv;
        if (jj == 1) {
          xv = spin_pair(xq + 1 * 256 + tid, want);
        } else {
          float a, b, r3;
          spin3(pza + tid, pzb + tid, pxp + tid, want, a, b, r3);
          xv = fmaxf(a + b + bprev + r3, 0.f);
        }
        s_x[tid] = xv;
        if (side == 0) {
          stc(ringj + (t & maskj) * 256 + tid, xv);       // for tap helper
          if (jj >= 2) stq(xout + tid, xv, want);         // early x publish
        }
      } else if (tid < 384) {
        int l = tid - 256;
        s_tap[l] = spin_pair(ptap + (t & 31) * 256 + base + l, want);
      }
      __syncthreads();
      { int r = tid & 127, s = tid >> 7;
        float acc = 0.f;
#pragma unroll
        for (int i = 0; i < 64; ++i) acc += wpv[i] * s_x[64 * s + i];
        s_p[s * 128 + r] = acc; }
      __syncthreads();
      if (tid < 128) {
        int f = t >> 7;
        float hv = s_p[tid] + s_p[128 + tid] + s_p[256 + tid] + s_p[384 + tid]
                 + s_cond[f * 128 + tid] + s_tap[tid];
        s_h[tid] = fmaxf(hv, 0.f);
      }
      __syncthreads();
      { int cc = tid & 255, s2 = tid >> 8;
        float acc = 0.f;
#pragma unroll
        for (int i = 0; i < 64; ++i) acc += wov[i] * s_h[64 * s2 + i];
        s_p[s2 * 256 + cc] = acc; }
      __syncthreads();
      if (side == 0)
        __builtin_amdgcn_fence(__ATOMIC_RELEASE, "agent");  // ring visible before z tag
      if (tid < 256) stq(zout + tid, s_p[tid] + s_p[256 + tid], want);
    }

  } else {
    // ------------------------- tap helpers (j = 1..10) ----------------------
    const int j = role - 21;
    const int dj = 1 << j, maskj = 2 * dj - 1;
    v64f wq0, wq1;
    { const float* W = WV_past + j * 65536;
      int r = tid & 255, s2 = tid >> 8;
#pragma unroll
      for (int i = 0; i < 64; ++i) wq0[i] = W[r * 256 + 128 * s2 + i];
#pragma unroll
      for (int i = 0; i < 64; ++i) wq1[i] = W[r * 256 + 128 * s2 + 64 + i]; }
    float* ringj = ws + OFF_RINGS + 512 * (dj - 1);
    u64* tapj = tq + (j - 1) * 32 * 256;
    u64* pza = zq + (j * 2 + 0) * 256;
    u64* pzb = zq + (j * 2 + 1) * 256;

    for (int t = 0; t < T_STEPS; ++t) {
      int wgA = (t >= dj) ? (t - dj + 1) : (t - 31);
      if (wgA < t - 31) wgA = t - 31;
      int wgB = t - 31;
      if (tid < 256 && (wgA >= 1 || wgB >= 1))
        spin_tag2(pza + tid, pzb + tid, wgA, wgB);
      float tapv = 0.f;
      if (t >= dj) {
        if (tid < 256) s_x[tid] = ldc(ringj + ((t - dj) & maskj) * 256 + tid);
        __syncthreads();
        int r = tid & 255, s2 = tid >> 8;
        float acc = 0.f;
#pragma unroll
        for (int i = 0; i < 64; ++i) acc += wq0[i] * s_x[128 * s2 + i];
#pragma unroll
        for (int i = 0; i < 64; ++i) acc += wq1[i] * s_x[128 * s2 + 64 + i];
        s_p[s2 * 256 + r] = acc;
        __syncthreads();
        if (tid < 256) tapv = s_p[tid] + s_p[256 + tid];
      }
      if (tid < 256) stq(tapj + (t & 31) * 256 + tid, tapv, t + 1);
      __syncthreads();
    }
  }
}

extern "C" void kernel_launch(void* const* d_in, const int* in_sizes, int n_in,
                              void* d_out, int out_size, void* d_ws, size_t ws_size,
                              hipStream_t stream) {
  const float* y       = (const float*)d_in[0];
  const float* samples = (const float*)d_in[1];
  const float* emb_raw = (const float*)d_in[2];
  const float* condW   = (const float*)d_in[3];
  const float* WV_past = (const float*)d_in[4];
  const float* WV_pres = (const float*)d_in[5];
  const float* W_o_w   = (const float*)d_in[6];
  const float* W_o_b   = (const float*)d_in[7];
  const float* end_w   = (const float*)d_in[8];
  const float* end_b   = (const float*)d_in[9];
  (void)in_sizes; (void)n_in; (void)out_size; (void)ws_size;
  hipLaunchKernelGGL(fftnet_kernel, dim3(NROLE), dim3(512), 0, stream,
                     y, samples, emb_raw, condW, WV_past, WV_pres,
                     W_o_w, W_o_b, end_w, end_b, (int*)d_out, (float*)d_ws);
}

// Round 9
// 50478.299 us; speedup vs baseline: 1.7193x; 1.7193x over previous
//
#include <hip/hip_runtime.h>
#include <math.h>

// ---------------------------------------------------------------------------
// FastFFTNet autoregressive sampler on MI355X — round 9: 4-way layer split.
// R5-R7 analysis: stage cost = 1 HBM hop + ~1.7us of weight STREAMING from L2
// (compiler never keeps 128 floats/thread in VGPRs; VGPR=104 across 3 forcing
// attempts). This round halves per-thread weights to 64 (one v64f) by
// splitting each layer over 4 blocks (Qk: h rows [64k,64k+64) + Wo cols
// [64k,64k+64)), L0 over 2 blocks, sampler publishing a tagged idx pair.
// All FP association orders preserved bit-exactly vs R5/R6/R7 (passed).
// Comms: plain relaxed agent-scope tagged {value,step} pairs (proven class;
// CAS/RMW disproven in R8: 65.7 GB write storm; sc0 disproven R1/R4).
//
// Blocks (53): 0 sampler | 1,2 L0A/L0B | 3..42 Q(layer j=1..10, k=0..3)
//              | 43..52 helper_j (past taps)
// ---------------------------------------------------------------------------

#define T_STEPS 2048
#define NBLK    53

typedef unsigned long long u64;
typedef float v64f __attribute__((ext_vector_type(64)));

// ws float offsets
#define OFF_EMBT   0           // tanh(emb_raw)           [256][256]
#define OFF_WPET   65536       // WV_present[0] @ emb^T   [class][256]
#define OFF_WVPET  131072      // WV_past[0]    @ emb^T   [class][256]
#define OFF_RINGS  196608      // ring_j (plain f32) at +512*((1<<j)-1)
#define OFF_TAPQ   1244672     // u64 pairs [10][32][256]
#define OFF_ZQ4    1408512     // u64 pairs [11][4][256] (layer0 uses slots 0,1)
#define OFF_XQ     1431040     // u64 pairs [11][256]    (x_j from Q0, j=1..10)
#define OFF_IDXQ   1436672     // one u64 pair
#define WS_FLOATS  1436736

#define FBAR(r)  (32*(r))      // init barriers; poison-safe monotone

// ---- agent-scope plain relaxed prims (proven coherence class) -------------
__device__ __forceinline__ float ldc(const float* p) {
  int v = __hip_atomic_load((const int*)p, __ATOMIC_RELAXED, __HIP_MEMORY_SCOPE_AGENT);
  return __int_as_float(v);
}
__device__ __forceinline__ void stc(float* p, float x) {
  __hip_atomic_store((int*)p, __float_as_int(x), __ATOMIC_RELAXED, __HIP_MEMORY_SCOPE_AGENT);
}
__device__ __forceinline__ u64 ldq(const u64* p) {
  return __hip_atomic_load(p, __ATOMIC_RELAXED, __HIP_MEMORY_SCOPE_AGENT);
}
__device__ __forceinline__ void stq(u64* p, float v, int tag) {
  u64 x = (u64)(unsigned)__float_as_int(v) | ((u64)(unsigned)tag << 32);
  __hip_atomic_store(p, x, __ATOMIC_RELAXED, __HIP_MEMORY_SCOPE_AGENT);
}
__device__ __forceinline__ int ptag(u64 q) { return (int)(q >> 32); }
__device__ __forceinline__ float pval(u64 q) { return __int_as_float((int)(unsigned)q); }

__device__ __forceinline__ float spin_pair(const u64* p, int want) {
  int bud = 1 << 20; u64 q;
  do { q = ldq(p); } while (ptag(q) < want && --bud > 0);
  return pval(q);
}
__device__ __forceinline__ int spin_idx(const u64* p, int want) {
  int bud = 1 << 20; u64 q;
  do { q = ldq(p); } while (ptag(q) < want && --bud > 0);
  return __float_as_int(pval(q)) & 255;
}
__device__ __forceinline__ void spin3(const u64* p1, const u64* p2, const u64* p3,
                                      int want, float& v1, float& v2, float& v3) {
  int bud = 1 << 20; u64 q1, q2, q3; bool ok;
  do {
    q1 = ldq(p1); q2 = ldq(p2); q3 = ldq(p3);
    ok = (ptag(q1) >= want) & (ptag(q2) >= want) & (ptag(q3) >= want);
  } while (!ok && --bud > 0);
  v1 = pval(q1); v2 = pval(q2); v3 = pval(q3);
}
__device__ __forceinline__ void spin5(const u64* p0, const u64* p1, const u64* p2,
                                      const u64* p3, const u64* p4, int want,
                                      float& v0, float& v1, float& v2, float& v3, float& v4) {
  int bud = 1 << 20; u64 q0, q1, q2, q3, q4; bool ok;
  do {
    q0 = ldq(p0); q1 = ldq(p1); q2 = ldq(p2); q3 = ldq(p3); q4 = ldq(p4);
    ok = (ptag(q0) >= want) & (ptag(q1) >= want) & (ptag(q2) >= want)
       & (ptag(q3) >= want) & (ptag(q4) >= want);
  } while (!ok && --bud > 0);
  v0 = pval(q0); v1 = pval(q1); v2 = pval(q2); v3 = pval(q3); v4 = pval(q4);
}
__device__ __forceinline__ void spin_tag2(const u64* p1, const u64* p2, int w1, int w2) {
  int bud = 1 << 20; u64 q1, q2; bool ok;
  do {
    q1 = ldq(p1); q2 = ldq(p2);
    ok = (ptag(q1) >= w1) & (ptag(q2) >= w2);
  } while (!ok && --bud > 0);
}
// init-phase flag prims (proven)
__device__ __forceinline__ void wait1(int* f, int want) {
  int it = 0;
  while (__hip_atomic_load(f, __ATOMIC_RELAXED, __HIP_MEMORY_SCOPE_AGENT) < want) {
    if (++it > (1 << 22)) break;
  }
  (void)__hip_atomic_load(f, __ATOMIC_ACQUIRE, __HIP_MEMORY_SCOPE_AGENT);
}
__device__ __forceinline__ void post(int* f, int v) {
  __hip_atomic_store(f, v, __ATOMIC_RELEASE, __HIP_MEMORY_SCOPE_AGENT);
}

__global__ __launch_bounds__(512, 1)
void fftnet_kernel(const float* __restrict__ y, const float* __restrict__ samples,
                   const float* __restrict__ emb_raw, const float* __restrict__ condW,
                   const float* __restrict__ WV_past, const float* __restrict__ WV_present,
                   const float* __restrict__ W_o_w, const float* __restrict__ W_o_b,
                   const float* __restrict__ end_w, const float* __restrict__ end_b,
                   int* __restrict__ out, float* __restrict__ ws)
{
  const int tid = threadIdx.x;
  const int bid = blockIdx.x;
  int* iflags = (int*)(ws + WS_FLOATS);
  u64* zq4  = (u64*)(ws + OFF_ZQ4);
  u64* xq   = (u64*)(ws + OFF_XQ);
  u64* tq   = (u64*)(ws + OFF_TAPQ);
  u64* idxq = (u64*)(ws + OFF_IDXQ);

  __shared__ float s_x[256];
  __shared__ float s_h[256];
  __shared__ float s_p[1024];
  __shared__ float s_cond[2048];
  __shared__ float s_tap[64];
  __shared__ float s_m[320];
  __shared__ unsigned long long s_mask[8];

  // ---- init B: embt = tanh(emb_raw) ---------------------------------------
  for (int i = bid * 512 + tid; i < 65536; i += NBLK * 512)
    stc(ws + OFF_EMBT + i, tanhf(emb_raw[i]));
  __syncthreads();
  if (tid == 0) post(iflags + FBAR(bid), 1);
  if (tid < NBLK) wait1(iflags + FBAR(tid), 1);
  __syncthreads();

  // ---- init C: WPEt / WVP0Et tables ---------------------------------------
  for (int n = bid; n < 512; n += NBLK) {
    const float* wmat = (n < 256) ? WV_present : WV_past;  // layer-0 slice
    int cls = n & 255;
    int c = tid & 255, s2 = tid >> 8;
    float acc = 0.f;
    for (int k = 128 * s2; k < 128 * s2 + 128; ++k)
      acc += wmat[c * 256 + k] * ws[OFF_EMBT + cls * 256 + k];
    s_p[s2 * 256 + c] = acc;
    __syncthreads();
    if (tid < 256)
      stc(ws + ((n < 256) ? OFF_WPET : OFF_WVPET) + cls * 256 + tid, s_p[tid] + s_p[256 + tid]);
    __syncthreads();
  }
  __syncthreads();
  if (tid == 0) post(iflags + FBAR(bid), 2);
  if (tid < NBLK) wait1(iflags + FBAR(tid), 2);
  __syncthreads();
  __builtin_amdgcn_fence(__ATOMIC_ACQUIRE, "agent");   // invalidate stale L1
  __syncthreads();

  // =========================================================================
  if (bid == 0) {
    // ------------------------- sampler -------------------------------------
    const int c = tid & 255, s2 = tid >> 8;
    v64f we0, we1;
#pragma unroll
    for (int i = 0; i < 64; ++i) we0[i] = end_w[c * 256 + 128 * s2 + i];
#pragma unroll
    for (int i = 0; i < 64; ++i) we1[i] = end_w[c * 256 + 128 * s2 + 64 + i];
    const float eb = end_b[c];
    const float b10 = W_o_b[10 * 256 + c];
    const u64* pz0 = zq4 + (10 * 4 + 0) * 256;
    const u64* pz1 = zq4 + (10 * 4 + 1) * 256;
    const u64* pz2 = zq4 + (10 * 4 + 2) * 256;
    const u64* pz3 = zq4 + (10 * 4 + 3) * 256;
    const u64* pxq = xq + 10 * 256;
    const int lane = tid & 63, w = tid >> 6;
    if (tid == 0) stq(idxq, __int_as_float(127), 1);

    for (int t = 0; t < T_STEPS; ++t) {
      float u = samples[t];
      if (tid < 256) {
        float a, b, cc, d, r3;
        spin5(pz0 + tid, pz1 + tid, pz2 + tid, pz3 + tid, pxq + tid, t + 1, a, b, cc, d, r3);
        float s01 = a + b, s23 = cc + d;          // == zA, zB of R7 bitwise
        s_x[tid] = fmaxf(s01 + s23 + b10 + r3, 0.f);
      }
      __syncthreads();
      float acc = 0.f;
#pragma unroll
      for (int i = 0; i < 64; ++i) acc += we0[i] * s_x[128 * s2 + i];
#pragma unroll
      for (int i = 0; i < 64; ++i) acc += we1[i] * s_x[128 * s2 + 64 + i];
      s_p[s2 * 256 + c] = acc;
      __syncthreads();
      float logit = 0.f;
      if (tid < 256) logit = s_p[tid] + s_p[256 + tid] + eb;
      float vmax = (tid < 256) ? logit : -3.4e38f;
#pragma unroll
      for (int d2 = 32; d2 > 0; d2 >>= 1) vmax = fmaxf(vmax, __shfl_xor(vmax, d2, 64));
      if (lane == 0) s_m[280 + w] = vmax;
      __syncthreads();
      float mx = fmaxf(fmaxf(s_m[280], s_m[281]), fmaxf(s_m[282], s_m[283]));
      float e = (tid < 256) ? expf(logit - mx) : 0.f;
      float vs = e;
#pragma unroll
      for (int d2 = 32; d2 > 0; d2 >>= 1) vs += __shfl_xor(vs, d2, 64);
      if (lane == 0) s_m[288 + w] = vs;
      __syncthreads();
      float ssum = s_m[288] + s_m[289] + s_m[290] + s_m[291];
      float p = (tid < 256) ? (e / ssum) : 0.f;
      float v = p;
#pragma unroll
      for (int d2 = 1; d2 < 64; d2 <<= 1) {
        float o = __shfl_up(v, (unsigned)d2, 64);
        if (lane >= d2) v += o;
      }
      if (tid < 256 && lane == 63) s_m[256 + w] = v;
      __syncthreads();
      float offs = 0.f;
      if (tid < 256) for (int k = 0; k < w; ++k) offs += s_m[256 + k];
      float cum = v + offs;
      unsigned long long msk = __ballot(tid < 256 && (cum > u));
      if (lane == 0) s_mask[w] = msk;
      __syncthreads();
      if (tid == 0) {
        int idx = 0;
        for (int k = 0; k < 4; ++k) {
          unsigned long long m2 = s_mask[k];
          if (m2) { idx = k * 64 + (int)__builtin_ctzll(m2); break; }
        }
        stq(idxq, __int_as_float(idx), t + 2);
        out[t] = idx;
      }
      __syncthreads();
    }

  } else if (bid <= 2) {
    // ------------------------- L0A / L0B ------------------------------------
    const int side = bid - 1;              // 0: h[0:128), wo cols 0:128; 1: rest
    const int row = tid & 255, chunk = tid >> 8;   // chunk in {0,1}
    v64f wv;
#pragma unroll
    for (int i = 0; i < 64; ++i)
      wv[i] = W_o_w[row * 256 + side * 128 + chunk * 64 + i];
    for (int e = tid; e < 2048; e += 512) {
      int f = e >> 7, rr = e & 127;
      float a = 0.f;
      for (int q = 0; q < 80; ++q) a += condW[(side * 128 + rr) * 80 + q] * y[q * 16 + f];
      s_cond[f * 128 + rr] = a;
    }
    __syncthreads();
    u64* zout = zq4 + (0 * 4 + side) * 256;
    int pidx = 127;

    for (int t = 0; t < T_STEPS; ++t) {
      int idx = pidx;
      if (tid < 128) {
        float tapv = (t > 0) ? ws[OFF_WVPET + pidx * 256 + side * 128 + tid] : 0.f;
        idx = spin_idx(idxq, t + 1);
        float hv = s_cond[(t >> 7) * 128 + tid]
                 + ws[OFF_WPET + idx * 256 + side * 128 + tid] + tapv;
        s_h[tid] = fmaxf(hv, 0.f);
        if (tid == 0) s_m[300] = __int_as_float(idx);
      }
      __syncthreads();
      float acc = 0.f;
#pragma unroll
      for (int i = 0; i < 64; ++i) acc += wv[i] * s_h[64 * chunk + i];
      s_p[chunk * 256 + row] = acc;
      __syncthreads();
      if (tid < 256) stq(zout + tid, s_p[tid] + s_p[256 + tid], t + 1);
      pidx = (tid < 128) ? idx : __float_as_int(s_m[300]);
      __syncthreads();
    }

  } else if (bid <= 42) {
    // ------------------------- layer Qk (j = 1..10, k = 0..3) ---------------
    const int jj = 1 + ((bid - 3) >> 2);
    const int k  = (bid - 3) & 3;
    v64f wv;                                // wp frag (t<256) or wo frag (t>=256)
    if (tid < 256) {
      int r = tid & 63, s = tid >> 6;
#pragma unroll
      for (int i = 0; i < 64; ++i)
        wv[i] = WV_present[jj * 65536 + (64 * k + r) * 256 + 64 * s + i];
    } else {
      int row = tid - 256;
#pragma unroll
      for (int i = 0; i < 64; ++i)
        wv[i] = W_o_w[jj * 65536 + row * 256 + 64 * k + i];
    }
    const float bprev = W_o_b[(jj - 1) * 256 + (tid & 255)];
    for (int e = tid; e < 1024; e += 512) {
      int f = e >> 6, rr = e & 63;
      float a = 0.f;
      for (int q = 0; q < 80; ++q)
        a += condW[(jj * 256 + 64 * k + rr) * 80 + q] * y[q * 16 + f];
      s_cond[f * 64 + rr] = a;
    }
    __syncthreads();
    const int dj = 1 << jj, maskj = 2 * dj - 1;
    float* ringj = ws + OFF_RINGS + 512 * (dj - 1);
    const u64* pz0 = zq4 + ((jj - 1) * 4 + 0) * 256;
    const u64* pz1 = zq4 + ((jj - 1) * 4 + 1) * 256;
    const u64* pz2 = zq4 + ((jj - 1) * 4 + 2) * 256;
    const u64* pz3 = zq4 + ((jj - 1) * 4 + 3) * 256;
    const u64* pxp = xq + (jj - 1) * 256;
    u64* zout = zq4 + (jj * 4 + k) * 256;
    u64* xout = xq + jj * 256;
    const u64* ptap = tq + (jj - 1) * 32 * 256;

    for (int t = 0; t < T_STEPS; ++t) {
      const int want = t + 1;
      if (tid < 256) {
        float xv;
        if (jj == 1) {
          float a, b, iv;
          spin3(pz0 + tid, pz1 + tid, idxq, want, a, b, iv);
          int idx = __float_as_int(iv) & 255;
          // x1 = relu((zA0+zB0) + b0 + emb[idx]) — same association as R7 L0
          xv = fmaxf((a + b) + bprev + ws[OFF_EMBT + idx * 256 + tid], 0.f);
        } else {
          float a, b, cc, d, xp;
          spin5(pz0 + tid, pz1 + tid, pz2 + tid, pz3 + tid, pxp + tid, want, a, b, cc, d, xp);
          float s01 = a + b, s23 = cc + d;   // == zA, zB bitwise
          xv = fmaxf(s01 + s23 + bprev + xp, 0.f);
        }
        s_x[tid] = xv;
        if (k == 0) stq(xout + tid, xv, want);        // early x publish
      } else if (tid >= 384 && tid < 448) {
        int l = tid - 384;
        s_tap[l] = spin_pair(ptap + (t & 31) * 256 + 64 * k + l, want);
      }
      __syncthreads();
      if (tid < 256) {
        int r = tid & 63, s = tid >> 6;
        float acc = 0.f;
#pragma unroll
        for (int i = 0; i < 64; ++i) acc += wv[i] * s_x[64 * s + i];
        s_p[s * 64 + r] = acc;
      } else if (k == 0) {
        int row = tid - 256;
        stc(ringj + (t & maskj) * 256 + row, s_x[row]);  // x_j history for taps
      }
      __syncthreads();
      if (tid < 64) {
        float hv = s_p[tid] + s_p[64 + tid] + s_p[128 + tid] + s_p[192 + tid]
                 + s_cond[(t >> 7) * 64 + tid] + s_tap[tid];
        s_h[tid] = fmaxf(hv, 0.f);
      }
      __syncthreads();
      if (tid >= 256) {
        int row = tid - 256;
        float acc = 0.f;
#pragma unroll
        for (int i = 0; i < 64; ++i) acc += wv[i] * s_h[i];
        if (k == 0)
          __builtin_amdgcn_fence(__ATOMIC_RELEASE, "agent");  // ring before z tag
        stq(zout + row, acc, want);
      }
      __syncthreads();
    }

  } else {
    // ------------------------- tap helpers (j = 1..10) ----------------------
    const int j = bid - 42;
    const int dj = 1 << j, maskj = 2 * dj - 1;
    v64f wq0, wq1;
    { int r = tid & 255, s2 = tid >> 8;
#pragma unroll
      for (int i = 0; i < 64; ++i) wq0[i] = WV_past[j * 65536 + r * 256 + 128 * s2 + i];
#pragma unroll
      for (int i = 0; i < 64; ++i) wq1[i] = WV_past[j * 65536 + r * 256 + 128 * s2 + 64 + i]; }
    float* ringj = ws + OFF_RINGS + 512 * (dj - 1);
    u64* tapj = tq + (j - 1) * 32 * 256;
    const u64* z0 = zq4 + (j * 4 + 0) * 256;

    for (int t = 0; t < T_STEPS; ++t) {
      // gates: ring(t-dj) visible via z_{j,0} tag (fence-ordered, same thread);
      // slot reuse: consumer Q_{e>>6} past step t-32 via its zout tag.
      int g0 = t - 31;
      if (t >= dj && t - dj + 1 > g0) g0 = t - dj + 1;
      int gk = t - 31;
      if (tid < 256 && (g0 >= 1 || gk >= 1)) {
        const u64* zk = zq4 + (j * 4 + (tid >> 6)) * 256;
        spin_tag2(z0 + tid, zk + tid, g0, gk);
      }
      float tapv = 0.f;
      if (t >= dj) {
        if (tid < 256) s_x[tid] = ldc(ringj + ((t - dj) & maskj) * 256 + tid);
        __syncthreads();
        int r = tid & 255, s2 = tid >> 8;
        float acc = 0.f;
#pragma unroll
        for (int i = 0; i < 64; ++i) acc += wq0[i] * s_x[128 * s2 + i];
#pragma unroll
        for (int i = 0; i < 64; ++i) acc += wq1[i] * s_x[128 * s2 + 64 + i];
        s_p[s2 * 256 + r] = acc;
        __syncthreads();
        if (tid < 256) tapv = s_p[tid] + s_p[256 + tid];
      }
      if (tid < 256) stq(tapj + (t & 31) * 256 + tid, tapv, t + 1);
      __syncthreads();
    }
  }
}

extern "C" void kernel_launch(void* const* d_in, const int* in_sizes, int n_in,
                              void* d_out, int out_size, void* d_ws, size_t ws_size,
                              hipStream_t stream) {
  const float* y       = (const float*)d_in[0];
  const float* samples = (const float*)d_in[1];
  const float* emb_raw = (const float*)d_in[2];
  const float* condW   = (const float*)d_in[3];
  const float* WV_past = (const float*)d_in[4];
  const float* WV_pres = (const float*)d_in[5];
  const float* W_o_w   = (const float*)d_in[6];
  const float* W_o_b   = (const float*)d_in[7];
  const float* end_w   = (const float*)d_in[8];
  const float* end_b   = (const float*)d_in[9];
  (void)in_sizes; (void)n_in; (void)out_size; (void)ws_size;
  hipLaunchKernelGGL(fftnet_kernel, dim3(NBLK), dim3(512), 0, stream,
                     y, samples, emb_raw, condW, WV_past, WV_pres,
                     W_o_w, W_o_b, end_w, end_b, (int*)d_out, (float*)d_ws);
}